// Round 1
// 2018.205 us; speedup vs baseline: 1.1361x; 1.1361x over previous
//
#include <hip/hip_runtime.h>
#include <hip/hip_bf16.h>
#include <math.h>

// GPT-2 block: B=4 S=2048 E=2048 H=16 HD=128 M=8192.
// bf16 MFMA (16x16x32), fp32 accumulate. Causal mask hard-coded.
// R1: workspace cut 480MB -> 224MB (suspected ws overflow fault).
// R2 (this round):
//   - FF chunked over ROWS (2 x 4096) with full K=8192 Wp GEMM: out fp32 is
//     read-modify-written ONCE instead of 4x (saves ~400MB HBM traffic).
//   - Packed-causal score buffer, all 16 heads (71.3MB): row-block i keeps
//     only (i+1)*128 cols. Scores = 1 triangular launch (no dead blocks),
//     softmax = 1 launch, PV = 1 launch of 256 blocks (full chip).

typedef __bf16 bf16;
typedef __attribute__((ext_vector_type(8))) __bf16 bf16x8;
typedef __attribute__((ext_vector_type(4))) float f32x4;

#define GLOBAL_AS __attribute__((address_space(1)))
#define LDS_AS __attribute__((address_space(3)))

__device__ __forceinline__ void gl_lds16(const bf16* g, bf16* l) {
  __builtin_amdgcn_global_load_lds((const GLOBAL_AS void*)g, (LDS_AS void*)l, 16, 0, 0);
}

struct Acc { f32x4 v[4][4]; };

// 128x128 tile at (m0,n0). A: MxK row-major (lda). Bt: NxK row-major (ldb).
// 256 thr = 4 waves 2x2, each a 64x64 quadrant. K in 32-steps.
__device__ __forceinline__ void gemm_core(const bf16* __restrict__ A, long lda,
                                          const bf16* __restrict__ Bt, long ldb,
                                          int m0, int n0, int kbeg, int kend,
                                          bf16* sa, bf16* sb, Acc& acc) {
  const int t    = threadIdx.x;
  const int lane = t & 63;
  const int w    = t >> 6;
  const int wm   = (w >> 1) << 6;
  const int wn   = (w & 1) << 6;
  const int quad = lane >> 4;
  const int l15  = lane & 15;
  const int rowA = t >> 2;        // staging row 0..63
  const int kc   = (t & 3) << 3;  // staging col offset (8 elems)

#pragma unroll
  for (int i = 0; i < 4; i++)
#pragma unroll
    for (int j = 0; j < 4; j++)
      acc.v[i][j] = f32x4{0.f, 0.f, 0.f, 0.f};

  bf16* sa_w0 = &sa[(w << 6) * 8];
  bf16* sa_w1 = &sa[(256 + (w << 6)) * 8];
  bf16* sb_w0 = &sb[(w << 6) * 8];
  bf16* sb_w1 = &sb[(256 + (w << 6)) * 8];

  for (int k0 = kbeg; k0 < kend; k0 += 32) {
    const bf16* ga = A + (long)(m0 + rowA) * lda + (k0 + kc);
    const bf16* gb = Bt + (long)(n0 + rowA) * ldb + (k0 + kc);
    gl_lds16(ga, sa_w0);
    gl_lds16(ga + 64 * lda, sa_w1);
    gl_lds16(gb, sb_w0);
    gl_lds16(gb + 64 * ldb, sb_w1);
    __syncthreads();

    bf16x8 af[4], bfv[4];
#pragma unroll
    for (int i = 0; i < 4; i++)
      af[i] = *(const bf16x8*)&sa[(wm + i * 16 + l15) * 32 + quad * 8];
#pragma unroll
    for (int j = 0; j < 4; j++)
      bfv[j] = *(const bf16x8*)&sb[(wn + j * 16 + l15) * 32 + quad * 8];
#pragma unroll
    for (int i = 0; i < 4; i++)
#pragma unroll
      for (int j = 0; j < 4; j++)
        acc.v[i][j] = __builtin_amdgcn_mfma_f32_16x16x32_bf16(af[i], bfv[j], acc.v[i][j], 0, 0, 0);
    __syncthreads();
  }
}

// C/D: lane l, reg r -> row=(l>>4)*4+r, col=l&15
template <typename F>
__device__ __forceinline__ void epilogue(int m0, int n0, const Acc& acc, F f) {
  const int t = threadIdx.x;
  const int lane = t & 63;
  const int w = t >> 6;
  const int wm = (w >> 1) << 6, wn = (w & 1) << 6;
  const int quad = lane >> 4, l15 = lane & 15;
#pragma unroll
  for (int i = 0; i < 4; i++)
#pragma unroll
    for (int j = 0; j < 4; j++)
#pragma unroll
      for (int r = 0; r < 4; r++)
        f(m0 + wm + i * 16 + quad * 4 + r, n0 + wn + j * 16 + l15, acc.v[i][j][r]);
}

// -------- weight convert+transpose: src[R][C] fp32 -> dst[C][R] bf16 --------
__global__ void k_transpose_cast(const float* __restrict__ src, bf16* __restrict__ dst,
                                 int R, int C) {
  __shared__ float tile[32][33];
  const int c0 = blockIdx.x << 5, r0 = blockIdx.y << 5;
  const int tx = threadIdx.x, ty = threadIdx.y;
  for (int i = ty; i < 32; i += 8)
    tile[i][tx] = src[(long)(r0 + i) * C + (c0 + tx)];
  __syncthreads();
  for (int i = ty; i < 32; i += 8)
    dst[(long)(c0 + i) * R + (r0 + tx)] = (bf16)tile[tx][i];
}

// -------- layernorm over E=2048, fp32 in, bf16 out --------
__global__ void k_layernorm(const float* __restrict__ x, const float* __restrict__ g,
                            const float* __restrict__ bta, bf16* __restrict__ out) {
  __shared__ float red[8];
  const long row = blockIdx.x;
  const float* xr = x + row * 2048;
  const int t = threadIdx.x;
  float4 a = reinterpret_cast<const float4*>(xr)[t];
  float4 b4 = reinterpret_cast<const float4*>(xr)[t + 256];
  float va[8] = {a.x, a.y, a.z, a.w, b4.x, b4.y, b4.z, b4.w};
  float s = 0.f, ss = 0.f;
#pragma unroll
  for (int i = 0; i < 8; i++) { s += va[i]; ss += va[i] * va[i]; }
#pragma unroll
  for (int o = 32; o > 0; o >>= 1) { s += __shfl_xor(s, o, 64); ss += __shfl_xor(ss, o, 64); }
  if ((t & 63) == 0) { red[t >> 6] = s; red[4 + (t >> 6)] = ss; }
  __syncthreads();
  s = red[0] + red[1] + red[2] + red[3];
  ss = red[4] + red[5] + red[6] + red[7];
  const float mu = s * (1.f / 2048.f);
  const float rstd = rsqrtf(ss * (1.f / 2048.f) - mu * mu + 1e-5f);
  bf16* op = out + row * 2048;
#pragma unroll
  for (int c = 0; c < 4; c++) {
    int i0 = t * 4 + c;
    op[i0] = (bf16)((va[c] - mu) * rstd * g[i0] + bta[i0]);
    int i1 = 1024 + t * 4 + c;
    op[i1] = (bf16)((va[4 + c] - mu) * rstd * g[i1] + bta[i1]);
  }
}

// -------- QKV per batch: h_b[2048][2048] x WqkvT[6144][2048]^T --------
// q,k -> [H][S][D] (q scaled); v -> [H][D][S]
__global__ __launch_bounds__(256, 2) void k_gemm_qkv(
    const bf16* __restrict__ A, const bf16* __restrict__ Bt, const float* __restrict__ bias,
    bf16* __restrict__ q, bf16* __restrict__ k, bf16* __restrict__ v) {
  __shared__ bf16 sa[128 * 32], sb[128 * 32];
  const int m0 = blockIdx.y << 7, n0 = blockIdx.x << 7;
  Acc acc;
  gemm_core(A, 2048, Bt, 2048, m0, n0, 0, 2048, sa, sb, acc);
  epilogue(m0, n0, acc, [&](int row, int col, float val) {
    float vv = val + bias[col];
    const int which = col >> 11, hh = (col >> 7) & 15, d = col & 127;
    if (which == 0)
      q[((long)hh * 2048 + row) * 128 + d] = (bf16)(vv * 0.08838834764831845f);
    else if (which == 1)
      k[((long)hh * 2048 + row) * 128 + d] = (bf16)vv;
    else
      v[((long)hh * 128 + d) * 2048 + row] = (bf16)vv;
  });
}

// ---- packed-causal score buffer geometry ----
// Per head: row-block i (0..15) stores 128 rows x (i+1)*128 cols, row-major.
// rb_base(i) = 16384 * i*(i+1)/2 = 8192*i*(i+1) elems; per-head = 2,228,224 elems.
#define SC_HEAD 2228224L

// -------- scores: q x k^T, triangular grid, all 16 heads --------
__global__ __launch_bounds__(256, 2) void k_gemm_scores(
    const bf16* __restrict__ q, const bf16* __restrict__ kk, bf16* __restrict__ sc) {
  const int idx = blockIdx.x;  // 0..135 triangular
  int m = (int)((sqrtf(8.f * idx + 1.f) - 1.f) * 0.5f);
  if ((m + 1) * (m + 2) / 2 <= idx) m++;
  if (m * (m + 1) / 2 > idx) m--;
  const int n = idx - m * (m + 1) / 2;
  const int h = blockIdx.z;
  __shared__ bf16 sa[128 * 32], sb[128 * 32];
  const bf16* qb = q + (long)h * 2048 * 128;
  const bf16* kb = kk + (long)h * 2048 * 128;
  Acc acc;
  gemm_core(qb, 128, kb, 128, m << 7, n << 7, 0, 128, sa, sb, acc);
  const long lda_m = (long)(m + 1) << 7;
  bf16* scp = sc + (long)h * SC_HEAD + (long)m * (m + 1) * 8192;
  const int mbase = m << 7;
  epilogue(m << 7, n << 7, acc, [&](int row, int col, float val) {
    scp[(long)(row - mbase) * lda_m + col] = (bf16)val;
  });
}

// -------- causal softmax per row (packed layout), all heads --------
__global__ void k_softmax(bf16* __restrict__ sc) {
  __shared__ float red[8];
  const int sq = blockIdx.x, h = blockIdx.y;
  const int mb = sq >> 7;
  const int lda = (mb + 1) << 7;
  bf16* rowp = sc + (long)h * SC_HEAD + (long)mb * (mb + 1) * 8192 + (long)(sq & 127) * lda;
  const int L = sq + 1;
  const int Lpad = lda;
  const int t = threadIdx.x;
  float v[8];
  float mx = -3e38f;
#pragma unroll
  for (int i = 0; i < 8; i++) {
    int idx = t + (i << 8);
    v[i] = (idx < L) ? (float)rowp[idx] : -3e38f;
    mx = fmaxf(mx, v[i]);
  }
#pragma unroll
  for (int o = 32; o > 0; o >>= 1) mx = fmaxf(mx, __shfl_xor(mx, o, 64));
  if ((t & 63) == 0) red[t >> 6] = mx;
  __syncthreads();
  mx = fmaxf(fmaxf(red[0], red[1]), fmaxf(red[2], red[3]));
  float sum = 0.f;
#pragma unroll
  for (int i = 0; i < 8; i++) {
    int idx = t + (i << 8);
    if (idx < L) { v[i] = __expf(v[i] - mx); sum += v[i]; }
  }
#pragma unroll
  for (int o = 32; o > 0; o >>= 1) sum += __shfl_xor(sum, o, 64);
  if ((t & 63) == 0) red[4 + (t >> 6)] = sum;
  __syncthreads();
  sum = red[4] + red[5] + red[6] + red[7];
  const float inv = 1.f / sum;
#pragma unroll
  for (int i = 0; i < 8; i++) {
    int idx = t + (i << 8);
    if (idx < L) rowp[idx] = (bf16)(v[i] * inv);
    else if (idx < Lpad) rowp[idx] = (bf16)0.f;
  }
}

// -------- PV: P(packed) x vT^T, all 16 heads, 256 blocks --------
__global__ __launch_bounds__(256, 2) void k_gemm_pv(
    const bf16* __restrict__ sc, const bf16* __restrict__ v, bf16* __restrict__ attn) {
  __shared__ bf16 sa[128 * 32], sb[128 * 32];
  const int mb = blockIdx.x;  // 0..15 row-block
  const int h = blockIdx.y;   // 0..15 head
  const int lda = (mb + 1) << 7;
  const bf16* A = sc + (long)h * SC_HEAD + (long)mb * (mb + 1) * 8192;
  const bf16* Bt = v + (long)h * 128 * 2048;
  Acc acc;
  gemm_core(A, lda, Bt, 2048, 0, 0, 0, lda, sa, sb, acc);
  const int rbase = mb << 7;
  epilogue(0, 0, acc, [&](int row, int col, float val) {
    attn[((long)(rbase + row) * 16 + h) * 128 + col] = (bf16)val;
  });
}

// -------- Wo proj + residual -> x1 (= d_out slice) --------
__global__ __launch_bounds__(256, 2) void k_gemm_wo(
    const bf16* __restrict__ A, const bf16* __restrict__ Bt, const float* __restrict__ bias,
    const float* __restrict__ xin, float* __restrict__ x1) {
  __shared__ bf16 sa[128 * 32], sb[128 * 32];
  const int m0 = blockIdx.y << 7, n0 = blockIdx.x << 7;
  Acc acc;
  gemm_core(A, 2048, Bt, 2048, m0, n0, 0, 2048, sa, sb, acc);
  epilogue(m0, n0, acc, [&](int row, int col, float val) {
    long idx = (long)row * 2048 + col;
    x1[idx] = xin[idx] + val + bias[col];
  });
}

// -------- FC (row chunk): h2r[4096][2048] x WfcT[8192][2048]^T + gelu -> ff[4096][8192] --------
__global__ __launch_bounds__(256, 2) void k_gemm_fc(
    const bf16* __restrict__ A, const bf16* __restrict__ Bt, const float* __restrict__ bias,
    bf16* __restrict__ ff) {
  __shared__ bf16 sa[128 * 32], sb[128 * 32];
  const int m0 = blockIdx.y << 7, n0 = blockIdx.x << 7;
  Acc acc;
  gemm_core(A, 2048, Bt, 2048, m0, n0, 0, 2048, sa, sb, acc);
  epilogue(m0, n0, acc, [&](int row, int col, float val) {
    float u = val + bias[col];
    float cc = 0.7978845608028654f * (u + 0.044715f * u * u * u);
    float ge = 0.5f * u * (1.f + tanhf(cc));
    ff[(long)row * 8192 + col] = (bf16)ge;
  });
}

// -------- Wp (row chunk): ff[4096][8192] x WpT[2048][8192]^T, full K, single RMW --------
__global__ __launch_bounds__(256, 2) void k_gemm_wp(
    const bf16* __restrict__ A, const bf16* __restrict__ Bt, const float* __restrict__ bias,
    float* __restrict__ out) {
  __shared__ bf16 sa[128 * 32], sb[128 * 32];
  const int m0 = blockIdx.y << 7, n0 = blockIdx.x << 7;
  Acc acc;
  gemm_core(A, 8192, Bt, 8192, m0, n0, 0, 8192, sa, sb, acc);
  epilogue(m0, n0, acc, [&](int row, int col, float val) {
    long idx = (long)row * 2048 + col;
    out[idx] = out[idx] + val + bias[col];
  });
}

extern "C" void kernel_launch(void* const* d_in, const int* in_sizes, int n_in,
                              void* d_out, int out_size, void* d_ws, size_t ws_size,
                              hipStream_t stream) {
  const float* x     = (const float*)d_in[0];
  const float* ln1_g = (const float*)d_in[2];
  const float* ln1_b = (const float*)d_in[3];
  const float* Wqkv  = (const float*)d_in[4];
  const float* bqkv  = (const float*)d_in[5];
  const float* Wo    = (const float*)d_in[6];
  const float* bo    = (const float*)d_in[7];
  const float* ln2_g = (const float*)d_in[8];
  const float* ln2_b = (const float*)d_in[9];
  const float* Wfc   = (const float*)d_in[10];
  const float* bfc   = (const float*)d_in[11];
  const float* Wp    = (const float*)d_in[12];
  const float* bp    = (const float*)d_in[13];
  float* out = (float*)d_out;

  // workspace layout: ~228 MiB total
  char* p = (char*)d_ws;
  bf16* WqkvT = (bf16*)p; p += 6144L * 2048 * 2;      //  25.2 MB
  bf16* WoT   = (bf16*)p; p += 2048L * 2048 * 2;      //   8.4 MB
  bf16* WfcT  = (bf16*)p; p += 8192L * 2048 * 2;      //  33.6 MB
  bf16* WpT   = (bf16*)p; p += 2048L * 8192 * 2;      //  33.6 MB
  bf16* h     = (bf16*)p; p += 8192L * 2048 * 2;      //  33.6 MB (h2 shares)
  bf16* qb    = (bf16*)p; p += 16L * 2048 * 128 * 2;  //  8.4 MB per-batch
  bf16* kb    = (bf16*)p; p += 16L * 2048 * 128 * 2;
  bf16* vb    = (bf16*)p; p += 16L * 2048 * 128 * 2;
  bf16* attnb = (bf16*)p; p += 16L * 2048 * 128 * 2;
  bf16* sc    = (bf16*)p; p += 16L * SC_HEAD * 2;     //  71.3 MB (ff chunk shares: 67.1 MB)
  bf16* h2 = h;
  bf16* ff = sc;

  dim3 tb(32, 8);
  k_transpose_cast<<<dim3(192, 64), tb, 0, stream>>>(Wqkv, WqkvT, 2048, 6144);
  k_transpose_cast<<<dim3(64, 64), tb, 0, stream>>>(Wo, WoT, 2048, 2048);
  k_transpose_cast<<<dim3(256, 64), tb, 0, stream>>>(Wfc, WfcT, 2048, 8192);
  k_transpose_cast<<<dim3(64, 256), tb, 0, stream>>>(Wp, WpT, 8192, 2048);

  k_layernorm<<<8192, 256, 0, stream>>>(x, ln1_g, ln1_b, h);

  for (int b = 0; b < 4; b++) {
    const bf16* hb = h + (long)b * 2048 * 2048;
    k_gemm_qkv<<<dim3(48, 16), 256, 0, stream>>>(hb, WqkvT, bqkv, qb, kb, vb);
    k_gemm_scores<<<dim3(136, 1, 16), 256, 0, stream>>>(qb, kb, sc);
    k_softmax<<<dim3(2048, 16), 256, 0, stream>>>(sc);
    k_gemm_pv<<<dim3(16, 16), 256, 0, stream>>>(sc, vb, attnb);
    k_gemm_wo<<<dim3(16, 16), 256, 0, stream>>>(attnb, WoT, bo,
                                                x + (long)b * 2048 * 2048,
                                                out + (long)b * 2048 * 2048);
  }

  k_layernorm<<<8192, 256, 0, stream>>>(out, ln2_g, ln2_b, h2);

  for (int r = 0; r < 2; r++) {
    const bf16* h2r = h2 + (long)r * 4096 * 2048;
    k_gemm_fc<<<dim3(64, 32), 256, 0, stream>>>(h2r, WfcT, bfc, ff);
    k_gemm_wp<<<dim3(16, 32), 256, 0, stream>>>(ff, WpT, bp, out + (long)r * 4096 * 2048);
  }
}

// Round 3
// 1931.300 us; speedup vs baseline: 1.1872x; 1.0450x over previous
//
#include <hip/hip_runtime.h>
#include <hip/hip_bf16.h>
#include <math.h>

// GPT-2 block: B=4 S=2048 E=2048 H=16 HD=128 M=8192.
// R2: row-chunked FF (single out RMW), packed-causal scores, 1-launch attn stages.
// R3: 256x256 deep-pipelined GEMM — container failed (no diagnostics).
// R4 (this round): same 256x256 core but SYMMETRIC 2-deep pipeline (guide-
//   verified pattern): stage(kt+2) issued at ONE point per iteration after the
//   end barrier; vmcnt(8) at top keeps next tile's 8 loads in flight across
//   barriers. Removes the fragile split-restage whose correctness depended on
//   compiler not reordering two stage clusters. Swizzle/setprio/XCD kept.

typedef __bf16 bf16;
typedef __attribute__((ext_vector_type(8))) __bf16 bf16x8;
typedef __attribute__((ext_vector_type(4))) float f32x4;

#define GLOBAL_AS __attribute__((address_space(1)))
#define LDS_AS __attribute__((address_space(3)))

__device__ __forceinline__ void gl_lds16(const bf16* g, bf16* l) {
  __builtin_amdgcn_global_load_lds((const GLOBAL_AS void*)g, (LDS_AS void*)l, 16, 0, 0);
}

#define MFMA16 __builtin_amdgcn_mfma_f32_16x16x32_bf16

// ===================== 256x256 pipelined core =====================
// A: MxK row-major (lda), Bt: NxK row-major (ldb). 512 thr = 8 waves (2M x 4N),
// per-wave 128x64 output. BK=64, double-buffered 128KB LDS (A0 A1 B0 B1).
// Swizzle: LDS[row][cg] holds global[row][cg ^ (row&7)] (cg = 8-elem group);
// staging writes LINEAR LDS from pre-swizzled global cols; reads XOR back.
// Pipeline: prologue stages tiles 0,1. Iter kt: vmcnt(8) [tile kt landed,
// tile kt+1 in flight] -> barrier -> ds_read frags -> 64 MFMA -> barrier
// [all waves done reading buf cur] -> stage tile kt+2 into buf cur.
__device__ __forceinline__ void gemm256_core(const bf16* __restrict__ A, long lda,
                                             const bf16* __restrict__ Bt, long ldb,
                                             int m0, int n0, int K,
                                             f32x4 (&acc)[8][4]) {
  __shared__ bf16 lds[65536];  // 128 KiB: A0 A1 B0 B1, 16384 elems each
  const int t = threadIdx.x;
  const int lane = t & 63;
  const int w = t >> 6;
  const int wm = (w >> 2) << 7;  // 0 / 128
  const int wn = (w & 3) << 6;   // 0 / 64 / 128 / 192
  const int quad = lane >> 4;
  const int l15 = lane & 15;

#pragma unroll
  for (int i = 0; i < 8; i++)
#pragma unroll
    for (int j = 0; j < 4; j++) acc[i][j] = f32x4{0.f, 0.f, 0.f, 0.f};

  // ---- read addressing (elems): row r at r*64, col (quad*8 [^32]) ^ ((r&7)*8)
  const int axor = (l15 & 7) << 3;
  const int c0 = (quad << 3) ^ axor;
  const int aroff = (wm + l15) << 6;   // + i*1024 per 16-row step
  const int broff = (wn + l15) << 6;   // + j*1024

  // ---- stage addressing: linear LDS dest (wave-uniform + lane*16B),
  //      pre-swizzled global source col (involution) ----
  const int srow = (w << 3) + (lane >> 3);           // 0..63 within 64-row chunk
  const int scol = ((lane & 7) ^ (lane >> 3)) << 3;  // global col-group ^ (row&7)
  const bf16* gA = A + (long)(m0 + srow) * lda + scol;
  const bf16* gB = Bt + (long)(n0 + srow) * ldb + scol;
  const int sdst = w << 9;  // wave-uniform elem offset; HW adds lane*8 elems

  const int NK = K >> 6;

  auto stage = [&](int buf, int kt) {
    const bf16* ga = gA + (long)kt * 64;
    const bf16* gb = gB + (long)kt * 64;
    bf16* da = lds + buf * 16384 + sdst;
    bf16* db = lds + 32768 + buf * 16384 + sdst;
#pragma unroll
    for (int c = 0; c < 4; c++) gl_lds16(ga + (long)(c * 64) * lda, da + c * 4096);
#pragma unroll
    for (int c = 0; c < 4; c++) gl_lds16(gb + (long)(c * 64) * ldb, db + c * 4096);
  };

  // prologue: FIFO = [A0 B0 (8), A1 B1 (8)]
  stage(0, 0);
  if (NK > 1) stage(1, 1);

  for (int kt = 0; kt < NK; ++kt) {
    const int cur = kt & 1;
    const bf16* sa = lds + cur * 16384;
    const bf16* sb = lds + 32768 + cur * 16384;

    // tile kt landed (oldest 8 retired); tile kt+1's 8 stay in flight
    if (kt + 1 < NK) asm volatile("s_waitcnt vmcnt(8)" ::: "memory");
    else             asm volatile("s_waitcnt vmcnt(0)" ::: "memory");
    __builtin_amdgcn_sched_barrier(0);
    __builtin_amdgcn_s_barrier();
    asm volatile("" ::: "memory");

    // B fragments for whole iteration (8 x ds_read_b128)
    bf16x8 b0[4], b1[4];
#pragma unroll
    for (int j = 0; j < 4; j++) {
      b0[j] = *(const bf16x8*)&sb[broff + j * 1024 + c0];
      b1[j] = *(const bf16x8*)&sb[broff + j * 1024 + (c0 ^ 32)];
    }
    // 4 phases: A row-pairs (2 rows x 2 k-slices each), 16 MFMA per phase
#pragma unroll
    for (int p = 0; p < 4; p++) {
      bf16x8 a00 = *(const bf16x8*)&sa[aroff + (2 * p + 0) * 1024 + c0];
      bf16x8 a01 = *(const bf16x8*)&sa[aroff + (2 * p + 0) * 1024 + (c0 ^ 32)];
      bf16x8 a10 = *(const bf16x8*)&sa[aroff + (2 * p + 1) * 1024 + c0];
      bf16x8 a11 = *(const bf16x8*)&sa[aroff + (2 * p + 1) * 1024 + (c0 ^ 32)];
      __builtin_amdgcn_s_setprio(1);
#pragma unroll
      for (int j = 0; j < 4; j++) {
        acc[2 * p + 0][j] = MFMA16(a00, b0[j], acc[2 * p + 0][j], 0, 0, 0);
        acc[2 * p + 0][j] = MFMA16(a01, b1[j], acc[2 * p + 0][j], 0, 0, 0);
        acc[2 * p + 1][j] = MFMA16(a10, b0[j], acc[2 * p + 1][j], 0, 0, 0);
        acc[2 * p + 1][j] = MFMA16(a11, b1[j], acc[2 * p + 1][j], 0, 0, 0);
      }
      __builtin_amdgcn_s_setprio(0);
    }

    asm volatile("" ::: "memory");
    __builtin_amdgcn_s_barrier();  // all waves done reading buf[cur]
    asm volatile("" ::: "memory");
    if (kt + 2 < NK) stage(cur, kt + 2);  // overwrite just-vacated buffer
  }
}

// C/D: row = wm + i*16 + quad*4 + r, col = wn + j*16 + l15
template <typename F>
__device__ __forceinline__ void epilogue256(int m0, int n0, const f32x4 (&acc)[8][4], F f) {
  const int t = threadIdx.x;
  const int lane = t & 63;
  const int w = t >> 6;
  const int wm = (w >> 2) << 7, wn = (w & 3) << 6;
  const int quad = lane >> 4, l15 = lane & 15;
#pragma unroll
  for (int i = 0; i < 8; i++)
#pragma unroll
    for (int j = 0; j < 4; j++)
#pragma unroll
      for (int r = 0; r < 4; r++)
        f(m0 + wm + i * 16 + quad * 4 + r, n0 + wn + j * 16 + l15, acc[i][j][r]);
}

// ===================== legacy 128x128 core (attn / wo) =====================
struct Acc { f32x4 v[4][4]; };

__device__ __forceinline__ void gemm_core(const bf16* __restrict__ A, long lda,
                                          const bf16* __restrict__ Bt, long ldb,
                                          int m0, int n0, int kbeg, int kend,
                                          bf16* sa, bf16* sb, Acc& acc) {
  const int t    = threadIdx.x;
  const int lane = t & 63;
  const int w    = t >> 6;
  const int wm   = (w >> 1) << 6;
  const int wn   = (w & 1) << 6;
  const int quad = lane >> 4;
  const int l15  = lane & 15;
  const int rowA = t >> 2;
  const int kc   = (t & 3) << 3;

#pragma unroll
  for (int i = 0; i < 4; i++)
#pragma unroll
    for (int j = 0; j < 4; j++)
      acc.v[i][j] = f32x4{0.f, 0.f, 0.f, 0.f};

  bf16* sa_w0 = &sa[(w << 6) * 8];
  bf16* sa_w1 = &sa[(256 + (w << 6)) * 8];
  bf16* sb_w0 = &sb[(w << 6) * 8];
  bf16* sb_w1 = &sb[(256 + (w << 6)) * 8];

  for (int k0 = kbeg; k0 < kend; k0 += 32) {
    const bf16* ga = A + (long)(m0 + rowA) * lda + (k0 + kc);
    const bf16* gb = Bt + (long)(n0 + rowA) * ldb + (k0 + kc);
    gl_lds16(ga, sa_w0);
    gl_lds16(ga + 64 * lda, sa_w1);
    gl_lds16(gb, sb_w0);
    gl_lds16(gb + 64 * ldb, sb_w1);
    __syncthreads();

    bf16x8 af[4], bfv[4];
#pragma unroll
    for (int i = 0; i < 4; i++)
      af[i] = *(const bf16x8*)&sa[(wm + i * 16 + l15) * 32 + quad * 8];
#pragma unroll
    for (int j = 0; j < 4; j++)
      bfv[j] = *(const bf16x8*)&sb[(wn + j * 16 + l15) * 32 + quad * 8];
#pragma unroll
    for (int i = 0; i < 4; i++)
#pragma unroll
      for (int j = 0; j < 4; j++)
        acc.v[i][j] = MFMA16(af[i], bfv[j], acc.v[i][j], 0, 0, 0);
    __syncthreads();
  }
}

template <typename F>
__device__ __forceinline__ void epilogue(int m0, int n0, const Acc& acc, F f) {
  const int t = threadIdx.x;
  const int lane = t & 63;
  const int w = t >> 6;
  const int wm = (w >> 1) << 6, wn = (w & 1) << 6;
  const int quad = lane >> 4, l15 = lane & 15;
#pragma unroll
  for (int i = 0; i < 4; i++)
#pragma unroll
    for (int j = 0; j < 4; j++)
#pragma unroll
      for (int r = 0; r < 4; r++)
        f(m0 + wm + i * 16 + quad * 4 + r, n0 + wn + j * 16 + l15, acc.v[i][j][r]);
}

// -------- weight convert+transpose: src[R][C] fp32 -> dst[C][R] bf16 --------
__global__ void k_transpose_cast(const float* __restrict__ src, bf16* __restrict__ dst,
                                 int R, int C) {
  __shared__ float tile[32][33];
  const int c0 = blockIdx.x << 5, r0 = blockIdx.y << 5;
  const int tx = threadIdx.x, ty = threadIdx.y;
  for (int i = ty; i < 32; i += 8)
    tile[i][tx] = src[(long)(r0 + i) * C + (c0 + tx)];
  __syncthreads();
  for (int i = ty; i < 32; i += 8)
    dst[(long)(c0 + i) * R + (r0 + tx)] = (bf16)tile[tx][i];
}

// -------- layernorm over E=2048, fp32 in, bf16 out --------
__global__ void k_layernorm(const float* __restrict__ x, const float* __restrict__ g,
                            const float* __restrict__ bta, bf16* __restrict__ out) {
  __shared__ float red[8];
  const long row = blockIdx.x;
  const float* xr = x + row * 2048;
  const int t = threadIdx.x;
  float4 a = reinterpret_cast<const float4*>(xr)[t];
  float4 b4 = reinterpret_cast<const float4*>(xr)[t + 256];
  float va[8] = {a.x, a.y, a.z, a.w, b4.x, b4.y, b4.z, b4.w};
  float s = 0.f, ss = 0.f;
#pragma unroll
  for (int i = 0; i < 8; i++) { s += va[i]; ss += va[i] * va[i]; }
#pragma unroll
  for (int o = 32; o > 0; o >>= 1) { s += __shfl_xor(s, o, 64); ss += __shfl_xor(ss, o, 64); }
  if ((t & 63) == 0) { red[t >> 6] = s; red[4 + (t >> 6)] = ss; }
  __syncthreads();
  s = red[0] + red[1] + red[2] + red[3];
  ss = red[4] + red[5] + red[6] + red[7];
  const float mu = s * (1.f / 2048.f);
  const float rstd = rsqrtf(ss * (1.f / 2048.f) - mu * mu + 1e-5f);
  bf16* op = out + row * 2048;
#pragma unroll
  for (int c = 0; c < 4; c++) {
    int i0 = t * 4 + c;
    op[i0] = (bf16)((va[c] - mu) * rstd * g[i0] + bta[i0]);
    int i1 = 1024 + t * 4 + c;
    op[i1] = (bf16)((va[4 + c] - mu) * rstd * g[i1] + bta[i1]);
  }
}

// -------- QKV per batch (256-core): h_b x WqkvT^T; q,k->[H][S][D], v->[H][D][S] --------
__global__ __launch_bounds__(512, 2) void k_qkv256(
    const bf16* __restrict__ A, const bf16* __restrict__ Bt, const float* __restrict__ bias,
    bf16* __restrict__ q, bf16* __restrict__ k, bf16* __restrict__ v) {
  const int bid = blockIdx.x;  // 192 = 8 row-tiles x 24 col-tiles
  const int swz = (bid & 7) * 24 + (bid >> 3);
  const int tx = swz % 24, ty = swz / 24;
  f32x4 acc[8][4];
  gemm256_core(A, 2048, Bt, 2048, ty << 8, tx << 8, 2048, acc);
  epilogue256(ty << 8, tx << 8, acc, [&](int row, int col, float val) {
    float vv = val + bias[col];
    const int which = col >> 11, hh = (col >> 7) & 15, d = col & 127;
    if (which == 0)
      q[((long)hh * 2048 + row) * 128 + d] = (bf16)(vv * 0.08838834764831845f);
    else if (which == 1)
      k[((long)hh * 2048 + row) * 128 + d] = (bf16)vv;
    else
      v[((long)hh * 128 + d) * 2048 + row] = (bf16)vv;
  });
}

// ---- packed-causal score buffer geometry ----
#define SC_HEAD 2228224L

// -------- scores: q x k^T, triangular grid, all 16 heads --------
__global__ __launch_bounds__(256, 2) void k_gemm_scores(
    const bf16* __restrict__ q, const bf16* __restrict__ kk, bf16* __restrict__ sc) {
  const int idx = blockIdx.x;  // 0..135 triangular
  int m = (int)((sqrtf(8.f * idx + 1.f) - 1.f) * 0.5f);
  if ((m + 1) * (m + 2) / 2 <= idx) m++;
  if (m * (m + 1) / 2 > idx) m--;
  const int n = idx - m * (m + 1) / 2;
  const int h = blockIdx.z;
  __shared__ bf16 sa[128 * 32], sb[128 * 32];
  const bf16* qb = q + (long)h * 2048 * 128;
  const bf16* kb = kk + (long)h * 2048 * 128;
  Acc acc;
  gemm_core(qb, 128, kb, 128, m << 7, n << 7, 0, 128, sa, sb, acc);
  const long lda_m = (long)(m + 1) << 7;
  bf16* scp = sc + (long)h * SC_HEAD + (long)m * (m + 1) * 8192;
  const int mbase = m << 7;
  epilogue(m << 7, n << 7, acc, [&](int row, int col, float val) {
    scp[(long)(row - mbase) * lda_m + col] = (bf16)val;
  });
}

// -------- causal softmax per row (packed layout), all heads --------
__global__ void k_softmax(bf16* __restrict__ sc) {
  __shared__ float red[8];
  const int sq = blockIdx.x, h = blockIdx.y;
  const int mb = sq >> 7;
  const int lda = (mb + 1) << 7;
  bf16* rowp = sc + (long)h * SC_HEAD + (long)mb * (mb + 1) * 8192 + (long)(sq & 127) * lda;
  const int L = sq + 1;
  const int Lpad = lda;
  const int t = threadIdx.x;
  float v[8];
  float mx = -3e38f;
#pragma unroll
  for (int i = 0; i < 8; i++) {
    int idx = t + (i << 8);
    v[i] = (idx < L) ? (float)rowp[idx] : -3e38f;
    mx = fmaxf(mx, v[i]);
  }
#pragma unroll
  for (int o = 32; o > 0; o >>= 1) mx = fmaxf(mx, __shfl_xor(mx, o, 64));
  if ((t & 63) == 0) red[t >> 6] = mx;
  __syncthreads();
  mx = fmaxf(fmaxf(red[0], red[1]), fmaxf(red[2], red[3]));
  float sum = 0.f;
#pragma unroll
  for (int i = 0; i < 8; i++) {
    int idx = t + (i << 8);
    if (idx < L) { v[i] = __expf(v[i] - mx); sum += v[i]; }
  }
#pragma unroll
  for (int o = 32; o > 0; o >>= 1) sum += __shfl_xor(sum, o, 64);
  if ((t & 63) == 0) red[4 + (t >> 6)] = sum;
  __syncthreads();
  sum = red[4] + red[5] + red[6] + red[7];
  const float inv = 1.f / sum;
#pragma unroll
  for (int i = 0; i < 8; i++) {
    int idx = t + (i << 8);
    if (idx < L) rowp[idx] = (bf16)(v[i] * inv);
    else if (idx < Lpad) rowp[idx] = (bf16)0.f;
  }
}

// -------- PV: P(packed) x vT^T, all 16 heads --------
__global__ __launch_bounds__(256, 2) void k_gemm_pv(
    const bf16* __restrict__ sc, const bf16* __restrict__ v, bf16* __restrict__ attn) {
  __shared__ bf16 sa[128 * 32], sb[128 * 32];
  const int mb = blockIdx.x;
  const int h = blockIdx.y;
  const int lda = (mb + 1) << 7;
  const bf16* A = sc + (long)h * SC_HEAD + (long)mb * (mb + 1) * 8192;
  const bf16* Bt = v + (long)h * 128 * 2048;
  Acc acc;
  gemm_core(A, lda, Bt, 2048, 0, 0, 0, lda, sa, sb, acc);
  const int rbase = mb << 7;
  epilogue(0, 0, acc, [&](int row, int col, float val) {
    attn[((long)(rbase + row) * 16 + h) * 128 + col] = (bf16)val;
  });
}

// -------- Wo proj + residual -> x1 (= d_out slice) --------
__global__ __launch_bounds__(256, 2) void k_gemm_wo(
    const bf16* __restrict__ A, const bf16* __restrict__ Bt, const float* __restrict__ bias,
    const float* __restrict__ xin, float* __restrict__ x1) {
  __shared__ bf16 sa[128 * 32], sb[128 * 32];
  const int m0 = blockIdx.y << 7, n0 = blockIdx.x << 7;
  Acc acc;
  gemm_core(A, 2048, Bt, 2048, m0, n0, 0, 2048, sa, sb, acc);
  epilogue(m0, n0, acc, [&](int row, int col, float val) {
    long idx = (long)row * 2048 + col;
    x1[idx] = xin[idx] + val + bias[col];
  });
}

// -------- FC (256-core, full M): h2 x WfcT^T + gelu -> ff[8192][8192] --------
__global__ __launch_bounds__(512, 2) void k_fc256(
    const bf16* __restrict__ A, const bf16* __restrict__ Bt, const float* __restrict__ bias,
    bf16* __restrict__ ff) {
  const int bid = blockIdx.x;  // 1024 = 32 row-tiles x 32 col-tiles
  const int swz = (bid & 7) * 128 + (bid >> 3);
  const int tx = swz & 31, ty = swz >> 5;
  f32x4 acc[8][4];
  gemm256_core(A, 2048, Bt, 2048, ty << 8, tx << 8, 2048, acc);
  epilogue256(ty << 8, tx << 8, acc, [&](int row, int col, float val) {
    float u = val + bias[col];
    float cc = 0.7978845608028654f * (u + 0.044715f * u * u * u);
    ff[(long)row * 8192 + col] = (bf16)(0.5f * u * (1.f + tanhf(cc)));
  });
}

// -------- Wp (256-core, full K=8192): ff x WpT^T + bias + single RMW out --------
__global__ __launch_bounds__(512, 2) void k_wp256(
    const bf16* __restrict__ A, const bf16* __restrict__ Bt, const float* __restrict__ bias,
    float* __restrict__ out) {
  const int bid = blockIdx.x;  // 256 = 32 row-tiles x 8 col-tiles
  const int swz = (bid & 7) * 32 + (bid >> 3);
  const int tx = swz & 7, ty = swz >> 3;
  f32x4 acc[8][4];
  gemm256_core(A, 8192, Bt, 8192, ty << 8, tx << 8, 8192, acc);
  epilogue256(ty << 8, tx << 8, acc, [&](int row, int col, float val) {
    long idx = (long)row * 2048 + col;
    out[idx] = out[idx] + val + bias[col];
  });
}

extern "C" void kernel_launch(void* const* d_in, const int* in_sizes, int n_in,
                              void* d_out, int out_size, void* d_ws, size_t ws_size,
                              hipStream_t stream) {
  const float* x     = (const float*)d_in[0];
  const float* ln1_g = (const float*)d_in[2];
  const float* ln1_b = (const float*)d_in[3];
  const float* Wqkv  = (const float*)d_in[4];
  const float* bqkv  = (const float*)d_in[5];
  const float* Wo    = (const float*)d_in[6];
  const float* bo    = (const float*)d_in[7];
  const float* ln2_g = (const float*)d_in[8];
  const float* ln2_b = (const float*)d_in[9];
  const float* Wfc   = (const float*)d_in[10];
  const float* bfc   = (const float*)d_in[11];
  const float* Wp    = (const float*)d_in[12];
  const float* bp    = (const float*)d_in[13];
  float* out = (float*)d_out;

  // workspace layout: ~239 MB total (same as R2). ff[8192][8192] (134.2MB)
  // aliases the attention-scratch region (WqkvT..sc = 138.4MB), dead before FF.
  char* p = (char*)d_ws;
  bf16* WfcT  = (bf16*)p; p += 8192L * 2048 * 2;      //  33.6 MB
  bf16* WpT   = (bf16*)p; p += 2048L * 8192 * 2;      //  33.6 MB
  bf16* h     = (bf16*)p; p += 8192L * 2048 * 2;      //  33.6 MB (h2 shares)
  char* ffreg = p;
  bf16* WqkvT = (bf16*)p; p += 6144L * 2048 * 2;      //  25.2 MB
  bf16* WoT   = (bf16*)p; p += 2048L * 2048 * 2;      //   8.4 MB
  bf16* qb    = (bf16*)p; p += 16L * 2048 * 128 * 2;  //   8.4 MB per-batch
  bf16* kb    = (bf16*)p; p += 16L * 2048 * 128 * 2;
  bf16* vb    = (bf16*)p; p += 16L * 2048 * 128 * 2;
  bf16* attnb = (bf16*)p; p += 16L * 2048 * 128 * 2;
  bf16* sc    = (bf16*)p; p += 16L * SC_HEAD * 2;     //  71.3 MB
  bf16* h2 = h;
  bf16* ff = (bf16*)ffreg;

  dim3 tb(32, 8);
  k_transpose_cast<<<dim3(192, 64), tb, 0, stream>>>(Wqkv, WqkvT, 2048, 6144);
  k_transpose_cast<<<dim3(64, 64), tb, 0, stream>>>(Wo, WoT, 2048, 2048);
  k_transpose_cast<<<dim3(256, 64), tb, 0, stream>>>(Wfc, WfcT, 2048, 8192);
  k_transpose_cast<<<dim3(64, 256), tb, 0, stream>>>(Wp, WpT, 8192, 2048);

  k_layernorm<<<8192, 256, 0, stream>>>(x, ln1_g, ln1_b, h);

  for (int b = 0; b < 4; b++) {
    const bf16* hb = h + (long)b * 2048 * 2048;
    k_qkv256<<<dim3(192), 512, 0, stream>>>(hb, WqkvT, bqkv, qb, kb, vb);
    k_gemm_scores<<<dim3(136, 1, 16), 256, 0, stream>>>(qb, kb, sc);
    k_softmax<<<dim3(2048, 16), 256, 0, stream>>>(sc);
    k_gemm_pv<<<dim3(16, 16), 256, 0, stream>>>(sc, vb, attnb);
    k_gemm_wo<<<dim3(16, 16), 256, 0, stream>>>(attnb, WoT, bo,
                                                x + (long)b * 2048 * 2048,
                                                out + (long)b * 2048 * 2048);
  }

  k_layernorm<<<8192, 256, 0, stream>>>(out, ln2_g, ln2_b, h2);

  k_fc256<<<dim3(1024), 512, 0, stream>>>(h2, WfcT, bfc, ff);
  k_wp256<<<dim3(256), 512, 0, stream>>>(ff, WpT, bp, out);
}